// Round 1
// baseline (87.646 us; speedup 1.0000x reference)
//
#include <hip/hip_runtime.h>
#include <hip/hip_bf16.h>

// KANGroup1D: out = id_gain[c]*x + spline(clamp(x*a[c]+b[c])) + bias[c]
// x: (B=16, C=192, H=128, W=128) fp32; alpha: (G=32, K=32); per-channel params (C,)
// group_idx: (C,) int32, maps channel -> alpha row.
//
// Memory-bound elementwise op. One block per (b,c) slice (H*W=16384 contiguous
// floats), float4 vectorized, alpha row staged in LDS.

#define Bdim 16
#define Cdim 192
#define HW   (128 * 128)
#define Kbins 32
#define CLAMP_V 1.5f

__device__ __forceinline__ float kan_one(float xv, float ac, float bc,
                                         float gc, float bsc,
                                         const float* __restrict__ s_alpha) {
    float xa = xv * ac + bc;
    xa = fminf(fmaxf(xa, -CLAMP_V), CLAMP_V);
    // u = (xa - LOW)/(HIGH-LOW)*(K-1) with LOW=-1, HIGH=1, K=32
    float u = (xa + 1.0f) * 15.5f;
    float fi = floorf(u);
    int i = (int)fi;
    float t = fminf(fmaxf(u - fi, 0.0f), 1.0f);
    int i0 = min(max(i - 1, 0), Kbins - 1);
    int i1 = min(max(i,     0), Kbins - 1);
    int i2 = min(max(i + 1, 0), Kbins - 1);
    int i3 = min(max(i + 2, 0), Kbins - 1);
    float t2 = t * t;
    float t3 = t2 * t;
    const float s = 1.0f / 6.0f;
    float w0 = (1.0f - 3.0f * t + 3.0f * t2 - t3) * s;
    float w1 = (4.0f - 6.0f * t2 + 3.0f * t3) * s;
    float w2 = (1.0f + 3.0f * t + 3.0f * t2 - 3.0f * t3) * s;
    float w3 = t3 * s;
    float sp = s_alpha[i0] * w0 + s_alpha[i1] * w1 +
               s_alpha[i2] * w2 + s_alpha[i3] * w3;
    return gc * xv + sp + bsc;
}

__global__ __launch_bounds__(256) void kan_group1d_kernel(
    const float4* __restrict__ x, const float* __restrict__ alpha,
    const float* __restrict__ a, const float* __restrict__ b,
    const float* __restrict__ id_gain, const float* __restrict__ bias,
    const int* __restrict__ group_idx, float4* __restrict__ out) {
    __shared__ float s_alpha[Kbins];

    const int slice = blockIdx.x;          // b*C + c
    const int c = slice % Cdim;

    if (threadIdx.x < Kbins) {
        int g = group_idx[c];
        s_alpha[threadIdx.x] = alpha[g * Kbins + threadIdx.x];
    }
    const float ac  = a[c];
    const float bc  = b[c];
    const float gc  = id_gain[c];
    const float bsc = bias[c];
    __syncthreads();

    const float4* xs = x   + (size_t)slice * (HW / 4);
    float4*       os = out + (size_t)slice * (HW / 4);

    #pragma unroll 4
    for (int idx = threadIdx.x; idx < HW / 4; idx += 256) {
        float4 v = xs[idx];
        float4 r;
        r.x = kan_one(v.x, ac, bc, gc, bsc, s_alpha);
        r.y = kan_one(v.y, ac, bc, gc, bsc, s_alpha);
        r.z = kan_one(v.z, ac, bc, gc, bsc, s_alpha);
        r.w = kan_one(v.w, ac, bc, gc, bsc, s_alpha);
        os[idx] = r;
    }
}

extern "C" void kernel_launch(void* const* d_in, const int* in_sizes, int n_in,
                              void* d_out, int out_size, void* d_ws, size_t ws_size,
                              hipStream_t stream) {
    const float4* x        = (const float4*)d_in[0];
    const float*  alpha    = (const float*)d_in[1];
    const float*  a        = (const float*)d_in[2];
    const float*  b        = (const float*)d_in[3];
    const float*  id_gain  = (const float*)d_in[4];
    const float*  bias     = (const float*)d_in[5];
    const int*    group_idx= (const int*)d_in[6];
    float4* out = (float4*)d_out;

    dim3 grid(Bdim * Cdim);   // 3072 blocks, one per (b,c) slice
    dim3 block(256);
    kan_group1d_kernel<<<grid, block, 0, stream>>>(x, alpha, a, b, id_gain,
                                                   bias, group_idx, out);
}

// Round 3
// 65.354 us; speedup vs baseline: 1.3411x; 1.3411x over previous
//
#include <hip/hip_runtime.h>
#include <hip/hip_bf16.h>

// KANGroup1D: out = id_gain[c]*x + spline(clamp(x*a[c]+b[c])) + bias[c]
// x: (B=16, C=192, H=128, W=128) fp32; alpha: (G=32, K=32)
//
// Round 3: per-bin cubic polynomial table in LDS (round-2 plan, fixed
// nontemporal-store type: clang builtin needs a NATIVE vector, not HIP's
// float4 class -> use ext_vector_type(4)).
//   u = (clamp(x*a+b, +-1.5) + 1) * 15.5  in [-7.75, 38.75] -> bin i in [-8,38]
//   spline(u) = c0[i] + c1[i]*t + c2[i]*t^2 + c3[i]*t^3,  t = u - floor(u)
// c[i] folds the 4 clamped alpha taps with the cubic B-spline basis.
// Per element: 1 ds_read_b128 + ~12 VALU ops (vs 4 ds_read_b32 + ~30 VALU).

#define Bdim 16
#define Cdim 192
#define HW   (128 * 128)
#define Kbins 32
#define NBINS 47            // i in [-8, 38], offset by +8
#define CLAMP_V 1.5f

typedef float f32x4 __attribute__((ext_vector_type(4)));

__global__ __launch_bounds__(256) void kan_group1d_kernel(
    const f32x4* __restrict__ x, const float* __restrict__ alpha,
    const float* __restrict__ a, const float* __restrict__ b,
    const float* __restrict__ id_gain, const float* __restrict__ bias,
    const int* __restrict__ group_idx, f32x4* __restrict__ out) {
    __shared__ float s_raw[Kbins];
    __shared__ f32x4 s_c[NBINS];

    const int slice = blockIdx.x;          // b*C + c
    const int c = slice % Cdim;
    const int tid = threadIdx.x;

    if (tid < Kbins) {
        int g = group_idx[c];
        s_raw[tid] = alpha[g * Kbins + tid];
    }
    __syncthreads();
    if (tid < NBINS) {
        int i = tid - 8;
        float a0 = s_raw[min(max(i - 1, 0), Kbins - 1)];
        float a1 = s_raw[min(max(i,     0), Kbins - 1)];
        float a2 = s_raw[min(max(i + 1, 0), Kbins - 1)];
        float a3 = s_raw[min(max(i + 2, 0), Kbins - 1)];
        const float s = 1.0f / 6.0f;
        f32x4 cc;
        cc.x = (a0 + 4.0f * a1 + a2) * s;
        cc.y = (3.0f * a2 - 3.0f * a0) * s;
        cc.z = (3.0f * a0 - 6.0f * a1 + 3.0f * a2) * s;
        cc.w = (3.0f * a1 - a0 - 3.0f * a2 + a3) * s;
        s_c[tid] = cc;
    }
    const float ac  = a[c];
    const float bc  = b[c];
    const float gc  = id_gain[c];
    const float bsc = bias[c];
    __syncthreads();

    const f32x4* xs = x   + (size_t)slice * (HW / 4);
    f32x4*       os = out + (size_t)slice * (HW / 4);

    #pragma unroll 8
    for (int idx = tid; idx < HW / 4; idx += 256) {
        f32x4 v = xs[idx];
        f32x4 r;
        #pragma unroll
        for (int e = 0; e < 4; ++e) {
            float xv = v[e];
            float xa = fminf(fmaxf(fmaf(xv, ac, bc), -CLAMP_V), CLAMP_V);
            float u  = fmaf(xa, 15.5f, 15.5f);
            float fi = floorf(u);
            float t  = u - fi;                 // in [0,1)
            int   bi = (int)fi + 8;            // [0, 46]
            f32x4 cc = s_c[bi];
            float sp = fmaf(t, fmaf(t, fmaf(t, cc.w, cc.z), cc.y), cc.x);
            r[e] = fmaf(gc, xv, sp + bsc);
        }
        __builtin_nontemporal_store(r, &os[idx]);
    }
}

extern "C" void kernel_launch(void* const* d_in, const int* in_sizes, int n_in,
                              void* d_out, int out_size, void* d_ws, size_t ws_size,
                              hipStream_t stream) {
    const f32x4* x         = (const f32x4*)d_in[0];
    const float*  alpha    = (const float*)d_in[1];
    const float*  a        = (const float*)d_in[2];
    const float*  b        = (const float*)d_in[3];
    const float*  id_gain  = (const float*)d_in[4];
    const float*  bias     = (const float*)d_in[5];
    const int*    group_idx= (const int*)d_in[6];
    f32x4* out = (f32x4*)d_out;

    dim3 grid(Bdim * Cdim);   // 3072 blocks, one per (b,c) slice
    dim3 block(256);
    kan_group1d_kernel<<<grid, block, 0, stream>>>(x, alpha, a, b, id_gain,
                                                   bias, group_idx, out);
}